// Round 1
// baseline (223.379 us; speedup 1.0000x reference)
//
#include <hip/hip_runtime.h>
#include <math.h>

#define N   8192
#define D   512
#define C   16
#define HM  256
#define HG  64
#define KMAX 128   // max neighbors per row (mean ~65, 12-sigma safe)

// ---------------- K1/K8: tiled f32 GEMM: Cout = act(A[M,K] @ W[K,Nc] (+bias)) ----------------
template<bool RELU, bool BIAS>
__global__ __launch_bounds__(256) void gemm_f32(const float* __restrict__ A,
    const float* __restrict__ W, const float* __restrict__ bias,
    float* __restrict__ Cout, int M, int K, int Nc) {
  __shared__ float As[16][68];  // [k][m], padded row (272B, 16B-aligned)
  __shared__ float Bs[16][64];  // [k][n]
  const int t = threadIdx.x;
  const int m0 = blockIdx.y * 64, n0 = blockIdx.x * 64;
  const int tm = t >> 4, tn = t & 15;
  float acc[4][4] = {};
  for (int kk = 0; kk < K; kk += 16) {
    {  // A tile: 64 rows x 16 cols; thread -> row t/4, float4 at (t%4)*4
      const float4 av = *(const float4*)&A[(size_t)(m0 + (t >> 2)) * K + kk + (t & 3) * 4];
      const int kc = (t & 3) * 4, mr = t >> 2;
      As[kc + 0][mr] = av.x; As[kc + 1][mr] = av.y;
      As[kc + 2][mr] = av.z; As[kc + 3][mr] = av.w;
    }
    {  // B tile: 16 rows x 64 cols; thread -> row t/16, float4 at (t%16)*4
      const float4 bv = *(const float4*)&W[(size_t)(kk + (t >> 4)) * Nc + n0 + (t & 15) * 4];
      *(float4*)&Bs[t >> 4][(t & 15) * 4] = bv;
    }
    __syncthreads();
    #pragma unroll
    for (int k = 0; k < 16; ++k) {
      const float4 a = *(const float4*)&As[k][tm * 4];
      const float4 b = *(const float4*)&Bs[k][tn * 4];
      const float av[4] = {a.x, a.y, a.z, a.w};
      const float bv[4] = {b.x, b.y, b.z, b.w};
      #pragma unroll
      for (int i = 0; i < 4; ++i)
        #pragma unroll
        for (int j = 0; j < 4; ++j)
          acc[i][j] = fmaf(av[i], bv[j], acc[i][j]);
    }
    __syncthreads();
  }
  #pragma unroll
  for (int i = 0; i < 4; ++i) {
    float4 o;
    float* op = (float*)&o;
    #pragma unroll
    for (int j = 0; j < 4; ++j) {
      float v = acc[i][j];
      if (BIAS) v += bias[n0 + tn * 4 + j];
      if (RELU) v = fmaxf(v, 0.f);
      op[j] = v;
    }
    *(float4*)&Cout[(size_t)(m0 + tm * 4 + i) * Nc + n0 + tn * 4] = o;
  }
}

// ---------------- K2: MLP head: B = softmax(C1 @ Wm2 + bm2); softy = mask ? onehot : B ----------
__global__ __launch_bounds__(256) void mlp_head(const float* __restrict__ C1,
    const float* __restrict__ Wm2, const float* __restrict__ bm2,
    const float* __restrict__ labels1h, const int* __restrict__ mask,
    float* __restrict__ Bmat, float* __restrict__ softy) {
  const int lane = threadIdx.x & 63;
  const int row = blockIdx.x * 4 + (threadIdx.x >> 6);
  const int c = lane & 15, grp = lane >> 4;
  float acc = 0.f;
  for (int k = grp * 64; k < grp * 64 + 64; ++k)
    acc = fmaf(C1[(size_t)row * HM + k], Wm2[k * C + c], acc);
  acc += __shfl_xor(acc, 16);
  acc += __shfl_xor(acc, 32);
  acc += bm2[c];
  float m = acc;
  for (int s = 1; s < 16; s <<= 1) m = fmaxf(m, __shfl_xor(m, s));
  const float e = __expf(acc - m);
  float ssum = e;
  for (int s = 1; s < 16; s <<= 1) ssum += __shfl_xor(ssum, s);
  const float b = e / ssum;
  if (lane < 16) {
    Bmat[row * C + c] = b;
    softy[row * C + c] = mask[row] ? labels1h[row * C + c] : b;
  }
}

// ---------------- K3: adj row scan -> ELL (deterministic ordered compaction) -------------------
__global__ __launch_bounds__(256) void adj_scan(const float* __restrict__ adj,
    int* __restrict__ rowcnt, int* __restrict__ colidx) {
  __shared__ unsigned short buf[256][8];
  __shared__ int scnt[256];
  const int t = threadIdx.x;
  const int row = blockIdx.x;
  const float4* arow = (const float4*)(adj + (size_t)row * N);
  int cnt = 0;
  #pragma unroll
  for (int p = 0; p < 8; ++p) {
    const float4 v = arow[p * 256 + t];
    const int base = (p * 256 + t) * 4;
    if (v.x > 0.f && cnt < 8) buf[t][cnt++] = (unsigned short)(base + 0);
    if (v.y > 0.f && cnt < 8) buf[t][cnt++] = (unsigned short)(base + 1);
    if (v.z > 0.f && cnt < 8) buf[t][cnt++] = (unsigned short)(base + 2);
    if (v.w > 0.f && cnt < 8) buf[t][cnt++] = (unsigned short)(base + 3);
  }
  scnt[t] = cnt;
  __syncthreads();
  // inclusive block scan
  for (int s = 1; s < 256; s <<= 1) {
    int add = 0;
    if (t >= s) add = scnt[t - s];
    __syncthreads();
    scnt[t] += add;
    __syncthreads();
  }
  const int off = scnt[t] - cnt;
  for (int i = 0; i < cnt; ++i) {
    const int pos = off + i;
    if (pos < KMAX) colidx[row * KMAX + pos] = (int)buf[t][i];
  }
  if (t == 255) rowcnt[row] = min(scnt[255], KMAX);
}

// ---------------- K4: nbrsum[j,:] = sum_{i in N(j)} softy[i,:]  (== Hm^T rows) -----------------
__global__ __launch_bounds__(256) void nbr_sum(const float* __restrict__ softy,
    const int* __restrict__ rowcnt, const int* __restrict__ colidx,
    float* __restrict__ nbrsum) {
  const int lane = threadIdx.x & 63;
  const int row = blockIdx.x * 4 + (threadIdx.x >> 6);
  const int c = lane & 15, grp = lane >> 4;
  const int cnt = rowcnt[row];
  float acc = 0.f;
  for (int e = grp; e < cnt; e += 4)
    acc += softy[colidx[row * KMAX + e] * C + c];
  acc += __shfl_xor(acc, 16);
  acc += __shfl_xor(acc, 32);
  if (lane < 16) nbrsum[row * C + c] = acc;
}

// ---------------- K5a: partial H[c,c'] and d[c] over 128-row slices ----------------------------
__global__ __launch_bounds__(256) void h_partial(const float* __restrict__ nbrsum,
    const float* __restrict__ softy, float* __restrict__ Hpart) {
  const int t = threadIdx.x;
  const int c = t >> 4, cp = t & 15;
  float acc = 0.f, dacc = 0.f;
  const int j0 = blockIdx.x * (N / 64);
  for (int j = j0; j < j0 + N / 64; ++j) {
    const float nv = nbrsum[j * C + c];
    acc = fmaf(nv, softy[j * C + cp], acc);
    if (cp == 0) dacc += nv;
  }
  Hpart[blockIdx.x * 272 + t] = acc;
  if (cp == 0) Hpart[blockIdx.x * 272 + 256 + c] = dacc;
}

// ---------------- K5b: H = Hun/d ; Q = rownorm((H H^T)*bias) ; write H,Q to d_out --------------
__global__ __launch_bounds__(256) void hq_final(const float* __restrict__ Hpart,
    const float* __restrict__ bias, float* __restrict__ H_out,
    float* __restrict__ Q_out, float* __restrict__ Qws) {
  __shared__ float Hs[256], Qs[256], rs[16], dd[16];
  const int t = threadIdx.x;
  const int c = t >> 4, cp = t & 15;
  float acc = 0.f;
  for (int b = 0; b < 64; ++b) acc += Hpart[b * 272 + t];
  if (t < 16) {
    float s = 0.f;
    for (int b = 0; b < 64; ++b) s += Hpart[b * 272 + 256 + t];
    dd[t] = s;
  }
  __syncthreads();
  const float Hv = acc / dd[c];
  Hs[t] = Hv;
  H_out[t] = Hv;
  __syncthreads();
  float q = 0.f;
  for (int k = 0; k < 16; ++k) q = fmaf(Hs[c * 16 + k], Hs[cp * 16 + k], q);
  q *= bias[t];
  Qs[t] = q;
  __syncthreads();
  if (t < 16) {
    float s = 0.f;
    for (int k = 0; k < 16; ++k) s += Qs[t * 16 + k];
    rs[t] = s;
  }
  __syncthreads();
  const float Qv = q / rs[c];
  Q_out[t] = Qv;
  Qws[t] = Qv;
}

// ---------------- K7: P=B@Q per row; edge scores; masked row softmax -> gval -------------------
__global__ __launch_bounds__(256) void edge_softmax(const float* __restrict__ Bmat,
    const float* __restrict__ Q, const int* __restrict__ rowcnt,
    const int* __restrict__ colidx, float* __restrict__ gval) {
  __shared__ float Prow[4][16];
  const int lane = threadIdx.x & 63, w = threadIdx.x >> 6;
  const int row = blockIdx.x * 4 + w;
  const int c = lane & 15, grp = lane >> 4;
  float acc = 0.f;
  for (int k = grp * 4; k < grp * 4 + 4; ++k)
    acc = fmaf(Bmat[row * C + k], Q[k * C + c], acc);
  acc += __shfl_xor(acc, 16);
  acc += __shfl_xor(acc, 32);
  if (lane < 16) Prow[w][c] = acc;
  __syncthreads();
  const int cnt = rowcnt[row];
  float s0 = -1e30f, s1 = -1e30f;
  if (lane < cnt) {
    const int col = colidx[row * KMAX + lane];
    float s = 0.f;
    for (int k = 0; k < 16; ++k) s = fmaf(Prow[w][k], Bmat[col * C + k], s);
    s0 = s;
  }
  if (lane + 64 < cnt) {
    const int col = colidx[row * KMAX + lane + 64];
    float s = 0.f;
    for (int k = 0; k < 16; ++k) s = fmaf(Prow[w][k], Bmat[col * C + k], s);
    s1 = s;
  }
  float m = fmaxf(s0, s1);
  for (int s = 1; s < 64; s <<= 1) m = fmaxf(m, __shfl_xor(m, s));
  const float e0 = __expf(s0 - m), e1 = __expf(s1 - m);
  float ssum = e0 + e1;
  for (int s = 1; s < 64; s <<= 1) ssum += __shfl_xor(ssum, s);
  const float inv = 1.f / ssum;
  if (lane < cnt) gval[row * KMAX + lane] = e0 * inv;
  if (lane + 64 < cnt) gval[row * KMAX + lane + 64] = e1 * inv;
}

// ---------------- K9: h = relu(g @ X1 + b1)  (lane = hidden channel) ---------------------------
__global__ __launch_bounds__(256) void gcn1(const float* __restrict__ X1,
    const float* __restrict__ b1, const int* __restrict__ rowcnt,
    const int* __restrict__ colidx, const float* __restrict__ gval,
    float* __restrict__ hbuf) {
  const int lane = threadIdx.x & 63;
  const int row = blockIdx.x * 4 + (threadIdx.x >> 6);
  const int cnt = rowcnt[row];
  float acc = 0.f;
  for (int e = 0; e < cnt; ++e) {
    const float g = gval[row * KMAX + e];
    const int col = colidx[row * KMAX + e];
    acc = fmaf(g, X1[(size_t)col * HG + lane], acc);
  }
  hbuf[(size_t)row * HG + lane] = fmaxf(acc + b1[lane], 0.f);
}

// ---------------- K10: X2 = h @ W2 -------------------------------------------------------------
__global__ __launch_bounds__(256) void x2_head(const float* __restrict__ hbuf,
    const float* __restrict__ W2, float* __restrict__ X2) {
  const int lane = threadIdx.x & 63;
  const int row = blockIdx.x * 4 + (threadIdx.x >> 6);
  const int c = lane & 15, grp = lane >> 4;
  float acc = 0.f;
  for (int k = grp * 16; k < grp * 16 + 16; ++k)
    acc = fmaf(hbuf[(size_t)row * HG + k], W2[k * C + c], acc);
  acc += __shfl_xor(acc, 16);
  acc += __shfl_xor(acc, 32);
  if (lane < 16) X2[row * C + c] = acc;
}

// ---------------- K11: output = g @ X2 + b2 ; logits = softmax(output) -------------------------
__global__ __launch_bounds__(256) void gcn2(const float* __restrict__ X2,
    const float* __restrict__ b2, const int* __restrict__ rowcnt,
    const int* __restrict__ colidx, const float* __restrict__ gval,
    float* __restrict__ out_logits, float* __restrict__ out_output) {
  const int lane = threadIdx.x & 63;
  const int row = blockIdx.x * 4 + (threadIdx.x >> 6);
  const int c = lane & 15, grp = lane >> 4;
  const int cnt = rowcnt[row];
  float acc = 0.f;
  for (int e = grp; e < cnt; e += 4)
    acc = fmaf(gval[row * KMAX + e], X2[colidx[row * KMAX + e] * C + c], acc);
  acc += __shfl_xor(acc, 16);
  acc += __shfl_xor(acc, 32);
  acc += b2[c];
  float m = acc;
  for (int s = 1; s < 16; s <<= 1) m = fmaxf(m, __shfl_xor(m, s));
  const float e = __expf(acc - m);
  float ssum = e;
  for (int s = 1; s < 16; s <<= 1) ssum += __shfl_xor(ssum, s);
  if (lane < 16) {
    out_output[row * C + c] = acc;
    out_logits[row * C + c] = e / ssum;
  }
}

// ---------------- K12: losses ------------------------------------------------------------------
__global__ __launch_bounds__(256) void loss_kernel(const float* __restrict__ logits,
    const float* __restrict__ Bmat, const int* __restrict__ idx,
    const int* __restrict__ label, float* __restrict__ out_loss) {
  __shared__ float sg[256], sm[256];
  const int t = threadIdx.x;
  float g = 0.f, m = 0.f;
  for (int i = t; i < 1024; i += 256) {
    const int ii = idx[i], ll = label[i];
    g -= logf(logits[ii * C + ll]);
    m -= logf(Bmat[ii * C + ll]);
  }
  sg[t] = g; sm[t] = m;
  __syncthreads();
  for (int s = 128; s > 0; s >>= 1) {
    if (t < s) { sg[t] += sg[t + s]; sm[t] += sm[t + s]; }
    __syncthreads();
  }
  if (t == 0) out_loss[0] = 1.0f * (sg[0] / 1024.f) + 1.0f * (sm[0] / 1024.f);
}

extern "C" void kernel_launch(void* const* d_in, const int* in_sizes, int n_in,
                              void* d_out, int out_size, void* d_ws, size_t ws_size,
                              hipStream_t stream) {
  const float* feature  = (const float*)d_in[0];
  const float* adj      = (const float*)d_in[1];
  const float* labels1h = (const float*)d_in[2];
  const float* bias     = (const float*)d_in[3];
  const float* Wm1 = (const float*)d_in[4];
  const float* bm1 = (const float*)d_in[5];
  const float* Wm2 = (const float*)d_in[6];
  const float* bm2 = (const float*)d_in[7];
  const float* W1  = (const float*)d_in[8];
  const float* b1  = (const float*)d_in[9];
  const float* W2  = (const float*)d_in[10];
  const float* b2  = (const float*)d_in[11];
  const int* idx   = (const int*)d_in[12];
  const int* label = (const int*)d_in[13];
  const int* mask  = (const int*)d_in[14];  // bool in ref; harness passes ints

  float* out = (float*)d_out;
  float* logits_o = out;                 // N*C
  float* loss_o   = out + (size_t)N * C; // 1
  float* H_o      = loss_o + 1;          // 256
  float* Q_o      = H_o + 256;           // 256
  float* outp_o   = Q_o + 256;           // N*C

  float* p = (float*)d_ws;
  float* C1     = p; p += (size_t)N * HM;   // 2,097,152
  float* X1     = p; p += (size_t)N * HG;   //   524,288
  float* hbuf   = p; p += (size_t)N * HG;   //   524,288
  float* Bmat   = p; p += (size_t)N * C;    //   131,072
  float* softy  = p; p += (size_t)N * C;
  float* nbrsum = p; p += (size_t)N * C;
  float* X2     = p; p += (size_t)N * C;
  float* Hpart  = p; p += 64 * 272;
  float* Qws    = p; p += 256;
  int* rowcnt = (int*)p; p += N;
  int* colidx = (int*)p; p += (size_t)N * KMAX;
  float* gval = p;                          // N*KMAX

  // MLP: C1 = relu(feature @ Wm1 + bm1)
  gemm_f32<true, true><<<dim3(HM / 64, N / 64), 256, 0, stream>>>(feature, Wm1, bm1, C1, N, D, HM);
  // B, softy
  mlp_head<<<N / 4, 256, 0, stream>>>(C1, Wm2, bm2, labels1h, mask, Bmat, softy);
  // sparse adjacency extraction (the one mandatory 256MB read)
  adj_scan<<<N, 256, 0, stream>>>(adj, rowcnt, colidx);
  // Hm rows
  nbr_sum<<<N / 4, 256, 0, stream>>>(softy, rowcnt, colidx, nbrsum);
  // H, Q
  h_partial<<<64, 256, 0, stream>>>(nbrsum, softy, Hpart);
  hq_final<<<1, 256, 0, stream>>>(Hpart, bias, H_o, Q_o, Qws);
  // edge scores + masked softmax
  edge_softmax<<<N / 4, 256, 0, stream>>>(Bmat, Qws, rowcnt, colidx, gval);
  // GCN
  gemm_f32<false, false><<<dim3(HG / 64, N / 64), 256, 0, stream>>>(feature, W1, nullptr, X1, N, D, HG);
  gcn1<<<N / 4, 256, 0, stream>>>(X1, b1, rowcnt, colidx, gval, hbuf);
  x2_head<<<N / 4, 256, 0, stream>>>(hbuf, W2, X2);
  gcn2<<<N / 4, 256, 0, stream>>>(X2, b2, rowcnt, colidx, gval, logits_o, outp_o);
  loss_kernel<<<1, 256, 0, stream>>>(logits_o, Bmat, idx, label, loss_o);
}

// Round 2
// 200.422 us; speedup vs baseline: 1.1145x; 1.1145x over previous
//
#include <hip/hip_runtime.h>
#include <math.h>

#define N   8192
#define D   512
#define C   16
#define HM  256
#define HG  64
#define KMAX 128   // max neighbors per row (mean ~65, 12-sigma safe)

typedef __attribute__((ext_vector_type(8))) short bf16x8;
typedef __attribute__((ext_vector_type(4))) float f32x4;

__device__ __forceinline__ unsigned short f2b(float x) {
  union { float f; unsigned int u; } v; v.f = x;
  unsigned int r = v.u + 0x7FFFu + ((v.u >> 16) & 1u);  // RNE
  return (unsigned short)(r >> 16);
}

// ---------------- K0a: feature f32 -> bf16 ------------------------------------------------------
__global__ __launch_bounds__(256) void f2bf_kernel(const float* __restrict__ in,
                                                   unsigned short* __restrict__ out) {
  const int i = blockIdx.x * 256 + threadIdx.x;  // one thread = 8 elems
  const float4 a = *(const float4*)&in[(size_t)i * 8];
  const float4 b = *(const float4*)&in[(size_t)i * 8 + 4];
  ushort4 lo, hi;
  lo.x = f2b(a.x); lo.y = f2b(a.y); lo.z = f2b(a.z); lo.w = f2b(a.w);
  hi.x = f2b(b.x); hi.y = f2b(b.y); hi.z = f2b(b.z); hi.w = f2b(b.w);
  *(ushort4*)&out[(size_t)i * 8] = lo;
  *(ushort4*)&out[(size_t)i * 8 + 4] = hi;
}

// ---------------- K0b: Wt[n][k] = bf16( n<256 ? Wm1[k][n] : W1[k][n-256] ) ---------------------
__global__ __launch_bounds__(256) void wcat_kernel(const float* __restrict__ Wm1,
    const float* __restrict__ W1, unsigned short* __restrict__ Wt) {
  const int idx = blockIdx.x * 256 + threadIdx.x;  // 320*512 = 163840
  const int n = idx >> 9, k = idx & 511;
  const float v = (n < 256) ? Wm1[k * 256 + n] : W1[k * 64 + (n - 256)];
  Wt[idx] = f2b(v);
}

// ---------------- K1: fused bf16 MFMA GEMM: [C1 | X1] = feature @ [Wm1 | W1] -------------------
// BM=64 (4 waves x 16 rows), BN=64. grid = (320/64, 8192/64).
__global__ __launch_bounds__(256) void gemm_mfma(const bf16x8* __restrict__ Abf,
    const bf16x8* __restrict__ Wt, const float* __restrict__ bm1,
    float* __restrict__ C1, float* __restrict__ X1) {
  const int l = threadIdx.x & 63, w = threadIdx.x >> 6;
  const int m0 = blockIdx.y * 64;
  const int n0 = blockIdx.x * 64;
  const int kb = l >> 4;          // k-block of 8 within K=32 step
  const int row = m0 + w * 16 + (l & 15);
  const bf16x8* arow = Abf + (size_t)row * 64 + kb;        // 512/8 = 64 chunks/row
  f32x4 acc[4] = {};
  #pragma unroll 4
  for (int kk = 0; kk < 16; ++kk) {                        // K-step of 32
    const bf16x8 af = arow[kk * 4];
    #pragma unroll
    for (int nt = 0; nt < 4; ++nt) {
      const bf16x8 bfr = Wt[(size_t)(n0 + nt * 16 + (l & 15)) * 64 + kk * 4 + kb];
      acc[nt] = __builtin_amdgcn_mfma_f32_16x16x32_bf16(af, bfr, acc[nt], 0, 0, 0);
    }
  }
  // C/D layout: col = lane&15, row = (lane>>4)*4 + reg
  const int orow = m0 + w * 16 + kb * 4;
  #pragma unroll
  for (int nt = 0; nt < 4; ++nt) {
    const int col = n0 + nt * 16 + (l & 15);
    #pragma unroll
    for (int r = 0; r < 4; ++r) {
      const float v = acc[nt][r];
      if (col < 256) C1[(size_t)(orow + r) * HM + col] = fmaxf(v + bm1[col], 0.f);
      else           X1[(size_t)(orow + r) * HG + (col - 256)] = v;
    }
  }
}

// ---------------- K2: MLP head: B = softmax(C1 @ Wm2 + bm2); softy = mask ? onehot : B ----------
__global__ __launch_bounds__(256) void mlp_head(const float* __restrict__ C1,
    const float* __restrict__ Wm2, const float* __restrict__ bm2,
    const float* __restrict__ labels1h, const int* __restrict__ mask,
    float* __restrict__ Bmat, float* __restrict__ softy) {
  const int lane = threadIdx.x & 63;
  const int row = blockIdx.x * 4 + (threadIdx.x >> 6);
  const int c = lane & 15, grp = lane >> 4;
  float acc = 0.f;
  for (int k = grp * 64; k < grp * 64 + 64; ++k)
    acc = fmaf(C1[(size_t)row * HM + k], Wm2[k * C + c], acc);
  acc += __shfl_xor(acc, 16);
  acc += __shfl_xor(acc, 32);
  acc += bm2[c];
  float m = acc;
  for (int s = 1; s < 16; s <<= 1) m = fmaxf(m, __shfl_xor(m, s));
  const float e = __expf(acc - m);
  float ssum = e;
  for (int s = 1; s < 16; s <<= 1) ssum += __shfl_xor(ssum, s);
  const float b = e / ssum;
  if (lane < 16) {
    Bmat[row * C + c] = b;
    softy[row * C + c] = mask[row] ? labels1h[row * C + c] : b;
  }
}

// ---------------- K3: adj row scan -> ELL (wave-scan ordered compaction) ------------------------
__global__ __launch_bounds__(256) void adj_scan(const float* __restrict__ adj,
    int* __restrict__ rowcnt, int* __restrict__ colidx) {
  __shared__ unsigned short buf[256][8];
  __shared__ int wsum[4];
  const int t = threadIdx.x, lane = t & 63, w = t >> 6;
  const int row = blockIdx.x;
  const float4* arow = (const float4*)(adj + (size_t)row * N);
  int cnt = 0;
  #pragma unroll
  for (int p = 0; p < 8; ++p) {
    const float4 v = arow[p * 256 + t];
    const int base = (p * 256 + t) * 4;
    if (v.x > 0.f && cnt < 8) buf[t][cnt++] = (unsigned short)(base + 0);
    if (v.y > 0.f && cnt < 8) buf[t][cnt++] = (unsigned short)(base + 1);
    if (v.z > 0.f && cnt < 8) buf[t][cnt++] = (unsigned short)(base + 2);
    if (v.w > 0.f && cnt < 8) buf[t][cnt++] = (unsigned short)(base + 3);
  }
  int x = cnt;
  #pragma unroll
  for (int s = 1; s < 64; s <<= 1) {
    const int y = __shfl_up(x, s);
    if (lane >= s) x += y;
  }
  if (lane == 63) wsum[w] = x;
  __syncthreads();
  int pre = 0;
  for (int i = 0; i < w; ++i) pre += wsum[i];
  const int off = pre + x - cnt;
  for (int i = 0; i < cnt; ++i)
    if (off + i < KMAX) colidx[row * KMAX + off + i] = (int)buf[t][i];
  if (t == 255) rowcnt[row] = min(pre + x, KMAX);
}

// ---------------- K4: nbrsum[j,:] = sum_{i in N(j)} softy[i,:]  (== Hm^T rows) -----------------
__global__ __launch_bounds__(256) void nbr_sum(const float* __restrict__ softy,
    const int* __restrict__ rowcnt, const int* __restrict__ colidx,
    float* __restrict__ nbrsum) {
  const int lane = threadIdx.x & 63;
  const int row = blockIdx.x * 4 + (threadIdx.x >> 6);
  const int c = lane & 15, grp = lane >> 4;
  const int cnt = rowcnt[row];
  float acc = 0.f;
  for (int e = grp; e < cnt; e += 4)
    acc += softy[colidx[row * KMAX + e] * C + c];
  acc += __shfl_xor(acc, 16);
  acc += __shfl_xor(acc, 32);
  if (lane < 16) nbrsum[row * C + c] = acc;
}

// ---------------- K5a: partial H[c,c'] and d[c] over row slices --------------------------------
__global__ __launch_bounds__(256) void h_partial(const float* __restrict__ nbrsum,
    const float* __restrict__ softy, float* __restrict__ Hpart) {
  const int t = threadIdx.x;
  const int c = t >> 4, cp = t & 15;
  float acc = 0.f, dacc = 0.f;
  const int j0 = blockIdx.x * (N / 64);
  for (int j = j0; j < j0 + N / 64; ++j) {
    const float nv = nbrsum[j * C + c];
    acc = fmaf(nv, softy[j * C + cp], acc);
    if (cp == 0) dacc += nv;
  }
  Hpart[blockIdx.x * 272 + t] = acc;
  if (cp == 0) Hpart[blockIdx.x * 272 + 256 + c] = dacc;
}

// ---------------- K5b: H = Hun/d ; Q = rownorm((H H^T)*bias) -----------------------------------
__global__ __launch_bounds__(256) void hq_final(const float* __restrict__ Hpart,
    const float* __restrict__ bias, float* __restrict__ H_out,
    float* __restrict__ Q_out, float* __restrict__ Qws) {
  __shared__ float Hs[256], Qs[256], rs[16], dd[16];
  const int t = threadIdx.x;
  const int c = t >> 4, cp = t & 15;
  float acc = 0.f;
  for (int b = 0; b < 64; ++b) acc += Hpart[b * 272 + t];
  if (t < 16) {
    float s = 0.f;
    for (int b = 0; b < 64; ++b) s += Hpart[b * 272 + 256 + t];
    dd[t] = s;
  }
  __syncthreads();
  const float Hv = acc / dd[c];
  Hs[t] = Hv;
  H_out[t] = Hv;
  __syncthreads();
  float q = 0.f;
  for (int k = 0; k < 16; ++k) q = fmaf(Hs[c * 16 + k], Hs[cp * 16 + k], q);
  q *= bias[t];
  Qs[t] = q;
  __syncthreads();
  if (t < 16) {
    float s = 0.f;
    for (int k = 0; k < 16; ++k) s += Qs[t * 16 + k];
    rs[t] = s;
  }
  __syncthreads();
  const float Qv = q / rs[c];
  Q_out[t] = Qv;
  Qws[t] = Qv;
}

// ---------------- K7: P=B@Q per row; edge scores; masked row softmax -> gval -------------------
__global__ __launch_bounds__(256) void edge_softmax(const float* __restrict__ Bmat,
    const float* __restrict__ Q, const int* __restrict__ rowcnt,
    const int* __restrict__ colidx, float* __restrict__ gval) {
  __shared__ float Prow[4][16];
  const int lane = threadIdx.x & 63, w = threadIdx.x >> 6;
  const int row = blockIdx.x * 4 + w;
  const int c = lane & 15, grp = lane >> 4;
  float acc = 0.f;
  for (int k = grp * 4; k < grp * 4 + 4; ++k)
    acc = fmaf(Bmat[row * C + k], Q[k * C + c], acc);
  acc += __shfl_xor(acc, 16);
  acc += __shfl_xor(acc, 32);
  if (lane < 16) Prow[w][c] = acc;
  __syncthreads();
  const int cnt = rowcnt[row];
  float s0 = -1e30f, s1 = -1e30f;
  if (lane < cnt) {
    const int col = colidx[row * KMAX + lane];
    float s = 0.f;
    for (int k = 0; k < 16; ++k) s = fmaf(Prow[w][k], Bmat[col * C + k], s);
    s0 = s;
  }
  if (lane + 64 < cnt) {
    const int col = colidx[row * KMAX + lane + 64];
    float s = 0.f;
    for (int k = 0; k < 16; ++k) s = fmaf(Prow[w][k], Bmat[col * C + k], s);
    s1 = s;
  }
  float m = fmaxf(s0, s1);
  for (int s = 1; s < 64; s <<= 1) m = fmaxf(m, __shfl_xor(m, s));
  const float e0 = __expf(s0 - m), e1 = __expf(s1 - m);
  float ssum = e0 + e1;
  for (int s = 1; s < 64; s <<= 1) ssum += __shfl_xor(ssum, s);
  const float inv = 1.f / ssum;
  if (lane < cnt) gval[row * KMAX + lane] = e0 * inv;
  if (lane + 64 < cnt) gval[row * KMAX + lane + 64] = e1 * inv;
}

// ---------------- K9: h = relu(g @ X1 + b1)  (lane = hidden channel) ---------------------------
__global__ __launch_bounds__(256) void gcn1(const float* __restrict__ X1,
    const float* __restrict__ b1, const int* __restrict__ rowcnt,
    const int* __restrict__ colidx, const float* __restrict__ gval,
    float* __restrict__ hbuf) {
  const int lane = threadIdx.x & 63;
  const int row = blockIdx.x * 4 + (threadIdx.x >> 6);
  const int cnt = rowcnt[row];
  float acc = 0.f;
  for (int e = 0; e < cnt; ++e) {
    const float g = gval[row * KMAX + e];
    const int col = colidx[row * KMAX + e];
    acc = fmaf(g, X1[(size_t)col * HG + lane], acc);
  }
  hbuf[(size_t)row * HG + lane] = fmaxf(acc + b1[lane], 0.f);
}

// ---------------- K10: X2 = h @ W2 -------------------------------------------------------------
__global__ __launch_bounds__(256) void x2_head(const float* __restrict__ hbuf,
    const float* __restrict__ W2, float* __restrict__ X2) {
  const int lane = threadIdx.x & 63;
  const int row = blockIdx.x * 4 + (threadIdx.x >> 6);
  const int c = lane & 15, grp = lane >> 4;
  float acc = 0.f;
  for (int k = grp * 16; k < grp * 16 + 16; ++k)
    acc = fmaf(hbuf[(size_t)row * HG + k], W2[k * C + c], acc);
  acc += __shfl_xor(acc, 16);
  acc += __shfl_xor(acc, 32);
  if (lane < 16) X2[row * C + c] = acc;
}

// ---------------- K11: output = g @ X2 + b2 ; logits = softmax(output) -------------------------
__global__ __launch_bounds__(256) void gcn2(const float* __restrict__ X2,
    const float* __restrict__ b2, const int* __restrict__ rowcnt,
    const int* __restrict__ colidx, const float* __restrict__ gval,
    float* __restrict__ out_logits, float* __restrict__ out_output) {
  const int lane = threadIdx.x & 63;
  const int row = blockIdx.x * 4 + (threadIdx.x >> 6);
  const int c = lane & 15, grp = lane >> 4;
  const int cnt = rowcnt[row];
  float acc = 0.f;
  for (int e = grp; e < cnt; e += 4)
    acc = fmaf(gval[row * KMAX + e], X2[colidx[row * KMAX + e] * C + c], acc);
  acc += __shfl_xor(acc, 16);
  acc += __shfl_xor(acc, 32);
  acc += b2[c];
  float m = acc;
  for (int s = 1; s < 16; s <<= 1) m = fmaxf(m, __shfl_xor(m, s));
  const float e = __expf(acc - m);
  float ssum = e;
  for (int s = 1; s < 16; s <<= 1) ssum += __shfl_xor(ssum, s);
  if (lane < 16) {
    out_output[row * C + c] = acc;
    out_logits[row * C + c] = e / ssum;
  }
}

// ---------------- K12: losses ------------------------------------------------------------------
__global__ __launch_bounds__(256) void loss_kernel(const float* __restrict__ logits,
    const float* __restrict__ Bmat, const int* __restrict__ idx,
    const int* __restrict__ label, float* __restrict__ out_loss) {
  __shared__ float sg[256], sm[256];
  const int t = threadIdx.x;
  float g = 0.f, m = 0.f;
  for (int i = t; i < 1024; i += 256) {
    const int ii = idx[i], ll = label[i];
    g -= logf(logits[ii * C + ll]);
    m -= logf(Bmat[ii * C + ll]);
  }
  sg[t] = g; sm[t] = m;
  __syncthreads();
  for (int s = 128; s > 0; s >>= 1) {
    if (t < s) { sg[t] += sg[t + s]; sm[t] += sm[t + s]; }
    __syncthreads();
  }
  if (t == 0) out_loss[0] = 1.0f * (sg[0] / 1024.f) + 1.0f * (sm[0] / 1024.f);
}

extern "C" void kernel_launch(void* const* d_in, const int* in_sizes, int n_in,
                              void* d_out, int out_size, void* d_ws, size_t ws_size,
                              hipStream_t stream) {
  const float* feature  = (const float*)d_in[0];
  const float* adj      = (const float*)d_in[1];
  const float* labels1h = (const float*)d_in[2];
  const float* bias     = (const float*)d_in[3];
  const float* Wm1 = (const float*)d_in[4];
  const float* bm1 = (const float*)d_in[5];
  const float* Wm2 = (const float*)d_in[6];
  const float* bm2 = (const float*)d_in[7];
  const float* W1  = (const float*)d_in[8];
  const float* b1  = (const float*)d_in[9];
  const float* W2  = (const float*)d_in[10];
  const float* b2  = (const float*)d_in[11];
  const int* idx   = (const int*)d_in[12];
  const int* label = (const int*)d_in[13];
  const int* mask  = (const int*)d_in[14];

  float* out = (float*)d_out;
  float* logits_o = out;                 // N*C
  float* loss_o   = out + (size_t)N * C; // 1
  float* H_o      = loss_o + 1;          // 256
  float* Q_o      = H_o + 256;           // 256
  float* outp_o   = Q_o + 256;           // N*C

  float* p = (float*)d_ws;
  float* C1     = p; p += (size_t)N * HM;   // all increments are multiples of 4 floats (16B)
  float* X1     = p; p += (size_t)N * HG;
  float* hbuf   = p; p += (size_t)N * HG;
  float* Bmat   = p; p += (size_t)N * C;
  float* softy  = p; p += (size_t)N * C;
  float* nbrsum = p; p += (size_t)N * C;
  float* X2     = p; p += (size_t)N * C;
  float* Hpart  = p; p += 64 * 272;
  float* Qws    = p; p += 256;
  int* rowcnt = (int*)p; p += N;
  int* colidx = (int*)p; p += (size_t)N * KMAX;
  float* gval = p; p += (size_t)N * KMAX;
  unsigned short* Abf = (unsigned short*)p;          // N*D bf16 = 8 MB
  unsigned short* Wt  = Abf + (size_t)N * D;         // 320*512 bf16

  // precision converts
  f2bf_kernel<<<(N * D / 8) / 256, 256, 0, stream>>>(feature, Abf);
  wcat_kernel<<<(320 * 512) / 256, 256, 0, stream>>>(Wm1, W1, Wt);
  // fused MFMA GEMM: [C1 | X1]
  gemm_mfma<<<dim3(320 / 64, N / 64), 256, 0, stream>>>((const bf16x8*)Abf, (const bf16x8*)Wt, bm1, C1, X1);
  // B, softy
  mlp_head<<<N / 4, 256, 0, stream>>>(C1, Wm2, bm2, labels1h, mask, Bmat, softy);
  // sparse adjacency extraction (the one mandatory 256MB read)
  adj_scan<<<N, 256, 0, stream>>>(adj, rowcnt, colidx);
  // Hm rows
  nbr_sum<<<N / 4, 256, 0, stream>>>(softy, rowcnt, colidx, nbrsum);
  // H, Q
  h_partial<<<64, 256, 0, stream>>>(nbrsum, softy, Hpart);
  hq_final<<<1, 256, 0, stream>>>(Hpart, bias, H_o, Q_o, Qws);
  // edge scores + masked softmax
  edge_softmax<<<N / 4, 256, 0, stream>>>(Bmat, Qws, rowcnt, colidx, gval);
  // GCN
  gcn1<<<N / 4, 256, 0, stream>>>(X1, b1, rowcnt, colidx, gval, hbuf);
  x2_head<<<N / 4, 256, 0, stream>>>(hbuf, W2, X2);
  gcn2<<<N / 4, 256, 0, stream>>>(X2, b2, rowcnt, colidx, gval, logits_o, outp_o);
  loss_kernel<<<1, 256, 0, stream>>>(logits_o, Bmat, idx, label, loss_o);
}

// Round 3
// 176.691 us; speedup vs baseline: 1.2642x; 1.1343x over previous
//
#include <hip/hip_runtime.h>
#include <math.h>

#define N   8192
#define D   512
#define C   16
#define HM  256
#define HG  64
#define KMAX 128   // max neighbors per row (mean ~65, 12-sigma safe)
#define INF 0x7FFFFFFF

typedef __attribute__((ext_vector_type(8))) short bf16x8;
typedef __attribute__((ext_vector_type(4))) float f32x4;

__device__ __forceinline__ unsigned short f2b(float x) {
  union { float f; unsigned int u; } v; v.f = x;
  unsigned int r = v.u + 0x7FFFu + ((v.u >> 16) & 1u);  // RNE
  return (unsigned short)(r >> 16);
}

// ---------------- K0: prep: feature->bf16, W concat->bf16 transposed, rowcnt=0 -----------------
__global__ __launch_bounds__(256) void prep_kernel(const float* __restrict__ feat,
    const float* __restrict__ Wm1, const float* __restrict__ W1,
    unsigned short* __restrict__ Abf, unsigned short* __restrict__ Wt,
    int* __restrict__ rowcnt) {
  const int tid = blockIdx.x * 256 + threadIdx.x;  // 524288 threads
  // feature convert: 8 elems/thread
  const float4 a = *(const float4*)&feat[(size_t)tid * 8];
  const float4 b = *(const float4*)&feat[(size_t)tid * 8 + 4];
  ushort4 lo, hi;
  lo.x = f2b(a.x); lo.y = f2b(a.y); lo.z = f2b(a.z); lo.w = f2b(a.w);
  hi.x = f2b(b.x); hi.y = f2b(b.y); hi.z = f2b(b.z); hi.w = f2b(b.w);
  *(ushort4*)&Abf[(size_t)tid * 8] = lo;
  *(ushort4*)&Abf[(size_t)tid * 8 + 4] = hi;
  // weight concat+transpose: Wt[n][k], n<256 -> Wm1, else W1
  if (tid < 320 * 512) {
    const int n = tid >> 9, k = tid & 511;
    const float v = (n < 256) ? Wm1[k * 256 + n] : W1[k * 64 + (n - 256)];
    Wt[tid] = f2b(v);
  }
  if (tid < N) rowcnt[tid] = 0;
}

// ---------------- K1: fused bf16 MFMA GEMM: [C1 | X1] = feature @ [Wm1 | W1] -------------------
__global__ __launch_bounds__(256) void gemm_mfma(const bf16x8* __restrict__ Abf,
    const bf16x8* __restrict__ Wt, const float* __restrict__ bm1,
    float* __restrict__ C1, float* __restrict__ X1) {
  const int l = threadIdx.x & 63, w = threadIdx.x >> 6;
  const int m0 = blockIdx.y * 64;
  const int n0 = blockIdx.x * 64;
  const int kb = l >> 4;
  const int row = m0 + w * 16 + (l & 15);
  const bf16x8* arow = Abf + (size_t)row * 64 + kb;
  f32x4 acc[4] = {};
  #pragma unroll 4
  for (int kk = 0; kk < 16; ++kk) {
    const bf16x8 af = arow[kk * 4];
    #pragma unroll
    for (int nt = 0; nt < 4; ++nt) {
      const bf16x8 bfr = Wt[(size_t)(n0 + nt * 16 + (l & 15)) * 64 + kk * 4 + kb];
      acc[nt] = __builtin_amdgcn_mfma_f32_16x16x32_bf16(af, bfr, acc[nt], 0, 0, 0);
    }
  }
  const int orow = m0 + w * 16 + kb * 4;
  #pragma unroll
  for (int nt = 0; nt < 4; ++nt) {
    const int col = n0 + nt * 16 + (l & 15);
    #pragma unroll
    for (int r = 0; r < 4; ++r) {
      const float v = acc[nt][r];
      if (col < 256) C1[(size_t)(orow + r) * HM + col] = fmaxf(v + bm1[col], 0.f);
      else           X1[(size_t)(orow + r) * HG + (col - 256)] = v;
    }
  }
}

// ---------------- K2: MLP head: B = softmax(C1 @ Wm2 + bm2); softy = mask ? onehot : B ----------
__global__ __launch_bounds__(256) void mlp_head(const float* __restrict__ C1,
    const float* __restrict__ Wm2, const float* __restrict__ bm2,
    const float* __restrict__ labels1h, const int* __restrict__ mask,
    float* __restrict__ Bmat, float* __restrict__ softy) {
  const int lane = threadIdx.x & 63;
  const int row = blockIdx.x * 4 + (threadIdx.x >> 6);
  const int c = lane & 15, grp = lane >> 4;
  float acc = 0.f;
  for (int k = grp * 64; k < grp * 64 + 64; ++k)
    acc = fmaf(C1[(size_t)row * HM + k], Wm2[k * C + c], acc);
  acc += __shfl_xor(acc, 16);
  acc += __shfl_xor(acc, 32);
  acc += bm2[c];
  float m = acc;
  for (int s = 1; s < 16; s <<= 1) m = fmaxf(m, __shfl_xor(m, s));
  const float e = __expf(acc - m);
  float ssum = e;
  for (int s = 1; s < 16; s <<= 1) ssum += __shfl_xor(ssum, s);
  const float b = e / ssum;
  if (lane < 16) {
    Bmat[row * C + c] = b;
    softy[row * C + c] = mask[row] ? labels1h[row * C + c] : b;
  }
}

// ---------------- K3: upper-triangle adj scan -> ELL via atomic append -------------------------
__global__ __launch_bounds__(256) void adj_tri(const float* __restrict__ adj,
    int* __restrict__ rowcnt, int* __restrict__ colidx) {
  const int row = blockIdx.x, t = threadIdx.x;
  const int c0 = row & ~3;                       // float4-aligned start covering the diagonal
  const int nch = (N - c0) >> 2;
  const float4* base = (const float4*)(adj + (size_t)row * N + c0);
  for (int p = t; p < nch; p += 256) {
    const float4 v = base[p];
    const int j = c0 + p * 4;
    const float vv[4] = {v.x, v.y, v.z, v.w};
    #pragma unroll
    for (int q = 0; q < 4; ++q) {
      const int jj = j + q;
      if (vv[q] > 0.f && jj >= row) {
        int pos = atomicAdd(&rowcnt[row], 1);
        if (pos < KMAX) colidx[row * KMAX + pos] = jj;
        if (jj > row) {
          pos = atomicAdd(&rowcnt[jj], 1);
          if (pos < KMAX) colidx[(size_t)jj * KMAX + pos] = row;
        }
      }
    }
  }
}

// ---------------- K4: per-row bitonic sort (determinism) + nbrsum ------------------------------
__global__ __launch_bounds__(256) void sort_nbr(int* __restrict__ rowcnt,
    int* __restrict__ colidx, const float* __restrict__ softy,
    float* __restrict__ nbrsum) {
  __shared__ int cs[4][128];
  const int lane = threadIdx.x & 63, w = threadIdx.x >> 6;
  const int row = blockIdx.x * 4 + w;
  const int cnt = min(rowcnt[row], KMAX);
  if (lane == 0) rowcnt[row] = cnt;  // clamp (deterministic rewrite)
  int e0 = (lane < cnt) ? colidx[row * KMAX + lane] : INF;
  int e1 = (lane + 64 < cnt) ? colidx[row * KMAX + lane + 64] : INF;
  // bitonic sort of 128 elements (2 regs/lane, positions lane & lane+64)
  #pragma unroll
  for (int k = 2; k <= 128; k <<= 1) {
    if (k == 128) { const int mn = min(e0, e1), mx = max(e0, e1); e0 = mn; e1 = mx; }
    #pragma unroll
    for (int j = (k == 128) ? 32 : (k >> 1); j > 0; j >>= 1) {
      const bool up = (lane & k) == 0;      // identical for pos lane+64 when k<=64? (see note)
      const bool upHi = ((lane + 64) & k) == 0;
      const bool lower = (lane & j) == 0;
      const int o0 = __shfl_xor(e0, j);
      const int o1 = __shfl_xor(e1, j);
      const int mn0 = min(e0, o0), mx0 = max(e0, o0);
      const int mn1 = min(e1, o1), mx1 = max(e1, o1);
      e0 = (up == lower) ? mn0 : mx0;
      e1 = (upHi == lower) ? mn1 : mx1;
    }
  }
  if (lane < cnt) colidx[row * KMAX + lane] = e0;
  if (lane + 64 < cnt) colidx[row * KMAX + lane + 64] = e1;
  cs[w][lane] = e0;
  cs[w][lane + 64] = e1;
  __syncthreads();
  // nbrsum[row,:] = sum over neighbors of softy
  const int c = lane & 15, grp = lane >> 4;
  float acc = 0.f;
  for (int e = grp; e < cnt; e += 4)
    acc += softy[cs[w][e] * C + c];
  acc += __shfl_xor(acc, 16);
  acc += __shfl_xor(acc, 32);
  if (lane < 16) nbrsum[row * C + c] = acc;
}

// ---------------- K5a: partial H[c,c'] and d[c] over row slices --------------------------------
__global__ __launch_bounds__(256) void h_partial(const float* __restrict__ nbrsum,
    const float* __restrict__ softy, float* __restrict__ Hpart) {
  const int t = threadIdx.x;
  const int c = t >> 4, cp = t & 15;
  float acc = 0.f, dacc = 0.f;
  const int j0 = blockIdx.x * (N / 64);
  for (int j = j0; j < j0 + N / 64; ++j) {
    const float nv = nbrsum[j * C + c];
    acc = fmaf(nv, softy[j * C + cp], acc);
    if (cp == 0) dacc += nv;
  }
  Hpart[blockIdx.x * 272 + t] = acc;
  if (cp == 0) Hpart[blockIdx.x * 272 + 256 + c] = dacc;
}

// ---------------- K5b: H = Hun/d ; Q = rownorm((H H^T)*bias) -----------------------------------
__global__ __launch_bounds__(256) void hq_final(const float* __restrict__ Hpart,
    const float* __restrict__ bias, float* __restrict__ H_out,
    float* __restrict__ Q_out, float* __restrict__ Qws) {
  __shared__ float Hs[256], Qs[256], rs[16], dd[16];
  const int t = threadIdx.x;
  const int c = t >> 4, cp = t & 15;
  float acc = 0.f;
  for (int b = 0; b < 64; ++b) acc += Hpart[b * 272 + t];
  if (t < 16) {
    float s = 0.f;
    for (int b = 0; b < 64; ++b) s += Hpart[b * 272 + 256 + t];
    dd[t] = s;
  }
  __syncthreads();
  const float Hv = acc / dd[c];
  Hs[t] = Hv;
  H_out[t] = Hv;
  __syncthreads();
  float q = 0.f;
  for (int k = 0; k < 16; ++k) q = fmaf(Hs[c * 16 + k], Hs[cp * 16 + k], q);
  q *= bias[t];
  Qs[t] = q;
  __syncthreads();
  if (t < 16) {
    float s = 0.f;
    for (int k = 0; k < 16; ++k) s += Qs[t * 16 + k];
    rs[t] = s;
  }
  __syncthreads();
  const float Qv = q / rs[c];
  Q_out[t] = Qv;
  Qws[t] = Qv;
}

// ---------------- K7: fused edge softmax + GCN layer1 + X2 head --------------------------------
__global__ __launch_bounds__(256) void edge_gcn1(const float* __restrict__ Bmat,
    const float* __restrict__ Q, const int* __restrict__ rowcnt,
    const int* __restrict__ colidx, const float* __restrict__ X1,
    const float* __restrict__ b1, const float* __restrict__ W2,
    float* __restrict__ gval, float* __restrict__ X2) {
  __shared__ float Prow[4][16];
  __shared__ float gv[4][128];
  __shared__ int cs[4][128];
  const int lane = threadIdx.x & 63, w = threadIdx.x >> 6;
  const int row = blockIdx.x * 4 + w;
  const int c = lane & 15, grp = lane >> 4;
  // P = Bmat[row,:] @ Q
  float acc = 0.f;
  for (int k = grp * 4; k < grp * 4 + 4; ++k)
    acc = fmaf(Bmat[row * C + k], Q[k * C + c], acc);
  acc += __shfl_xor(acc, 16);
  acc += __shfl_xor(acc, 32);
  if (lane < 16) Prow[w][c] = acc;
  __syncthreads();
  // edge scores + masked softmax
  const int cnt = rowcnt[row];
  const int col0 = (lane < cnt) ? colidx[row * KMAX + lane] : 0;
  const int col1 = (lane + 64 < cnt) ? colidx[row * KMAX + lane + 64] : 0;
  float s0 = -1e30f, s1 = -1e30f;
  if (lane < cnt) {
    float s = 0.f;
    for (int k = 0; k < 16; ++k) s = fmaf(Prow[w][k], Bmat[col0 * C + k], s);
    s0 = s;
  }
  if (lane + 64 < cnt) {
    float s = 0.f;
    for (int k = 0; k < 16; ++k) s = fmaf(Prow[w][k], Bmat[col1 * C + k], s);
    s1 = s;
  }
  float m = fmaxf(s0, s1);
  for (int s = 1; s < 64; s <<= 1) m = fmaxf(m, __shfl_xor(m, s));
  const float e0 = __expf(s0 - m), e1 = __expf(s1 - m);
  float ssum = e0 + e1;
  for (int s = 1; s < 64; s <<= 1) ssum += __shfl_xor(ssum, s);
  const float inv = 1.f / ssum;
  const float g0 = e0 * inv, g1 = e1 * inv;
  if (lane < cnt) gval[row * KMAX + lane] = g0;
  if (lane + 64 < cnt) gval[row * KMAX + lane + 64] = g1;
  gv[w][lane] = g0; gv[w][lane + 64] = g1;
  cs[w][lane] = col0; cs[w][lane + 64] = col1;
  __syncthreads();
  // GCN layer 1: h[lane] = relu(sum_e g_e * X1[col_e, lane] + b1[lane])
  float hacc = 0.f;
  for (int e = 0; e < cnt; ++e)
    hacc = fmaf(gv[w][e], X1[(size_t)cs[w][e] * HG + lane], hacc);
  const float h = fmaxf(hacc + b1[lane], 0.f);
  // X2[row,:] = h_row @ W2 : butterfly-reduce 16 partials across the wave
  float x[16];
  #pragma unroll
  for (int cc = 0; cc < 16; ++cc) x[cc] = h * W2[lane * C + cc];
  #pragma unroll
  for (int s = 1; s < 64; s <<= 1)
    #pragma unroll
    for (int cc = 0; cc < 16; ++cc) x[cc] += __shfl_xor(x[cc], s);
  float v = x[0];
  #pragma unroll
  for (int cc = 1; cc < 16; ++cc) v = (lane == cc) ? x[cc] : v;
  if (lane < 16) X2[row * C + lane] = v;
}

// ---------------- K11: output = g @ X2 + b2 ; logits = softmax(output) -------------------------
__global__ __launch_bounds__(256) void gcn2(const float* __restrict__ X2,
    const float* __restrict__ b2, const int* __restrict__ rowcnt,
    const int* __restrict__ colidx, const float* __restrict__ gval,
    float* __restrict__ out_logits, float* __restrict__ out_output) {
  const int lane = threadIdx.x & 63;
  const int row = blockIdx.x * 4 + (threadIdx.x >> 6);
  const int c = lane & 15, grp = lane >> 4;
  const int cnt = rowcnt[row];
  float acc = 0.f;
  for (int e = grp; e < cnt; e += 4)
    acc = fmaf(gval[row * KMAX + e], X2[colidx[row * KMAX + e] * C + c], acc);
  acc += __shfl_xor(acc, 16);
  acc += __shfl_xor(acc, 32);
  acc += b2[c];
  float m = acc;
  for (int s = 1; s < 16; s <<= 1) m = fmaxf(m, __shfl_xor(m, s));
  const float e = __expf(acc - m);
  float ssum = e;
  for (int s = 1; s < 16; s <<= 1) ssum += __shfl_xor(ssum, s);
  if (lane < 16) {
    out_output[row * C + c] = acc;
    out_logits[row * C + c] = e / ssum;
  }
}

// ---------------- K12: losses ------------------------------------------------------------------
__global__ __launch_bounds__(256) void loss_kernel(const float* __restrict__ logits,
    const float* __restrict__ Bmat, const int* __restrict__ idx,
    const int* __restrict__ label, float* __restrict__ out_loss) {
  __shared__ float sg[256], sm[256];
  const int t = threadIdx.x;
  float g = 0.f, m = 0.f;
  for (int i = t; i < 1024; i += 256) {
    const int ii = idx[i], ll = label[i];
    g -= logf(logits[ii * C + ll]);
    m -= logf(Bmat[ii * C + ll]);
  }
  sg[t] = g; sm[t] = m;
  __syncthreads();
  for (int s = 128; s > 0; s >>= 1) {
    if (t < s) { sg[t] += sg[t + s]; sm[t] += sm[t + s]; }
    __syncthreads();
  }
  if (t == 0) out_loss[0] = 1.0f * (sg[0] / 1024.f) + 1.0f * (sm[0] / 1024.f);
}

extern "C" void kernel_launch(void* const* d_in, const int* in_sizes, int n_in,
                              void* d_out, int out_size, void* d_ws, size_t ws_size,
                              hipStream_t stream) {
  const float* feature  = (const float*)d_in[0];
  const float* adj      = (const float*)d_in[1];
  const float* labels1h = (const float*)d_in[2];
  const float* bias     = (const float*)d_in[3];
  const float* Wm1 = (const float*)d_in[4];
  const float* bm1 = (const float*)d_in[5];
  const float* Wm2 = (const float*)d_in[6];
  const float* bm2 = (const float*)d_in[7];
  const float* W1  = (const float*)d_in[8];
  const float* b1  = (const float*)d_in[9];
  const float* W2  = (const float*)d_in[10];
  const float* b2  = (const float*)d_in[11];
  const int* idx   = (const int*)d_in[12];
  const int* label = (const int*)d_in[13];
  const int* mask  = (const int*)d_in[14];

  float* out = (float*)d_out;
  float* logits_o = out;                 // N*C
  float* loss_o   = out + (size_t)N * C; // 1
  float* H_o      = loss_o + 1;          // 256
  float* Q_o      = H_o + 256;           // 256
  float* outp_o   = Q_o + 256;           // N*C

  float* p = (float*)d_ws;
  float* C1     = p; p += (size_t)N * HM;
  float* X1     = p; p += (size_t)N * HG;
  float* Bmat   = p; p += (size_t)N * C;
  float* softy  = p; p += (size_t)N * C;
  float* nbrsum = p; p += (size_t)N * C;
  float* X2     = p; p += (size_t)N * C;
  float* Hpart  = p; p += 64 * 272;
  float* Qws    = p; p += 256;
  int* rowcnt = (int*)p; p += N;
  int* colidx = (int*)p; p += (size_t)N * KMAX;
  float* gval = p; p += (size_t)N * KMAX;
  unsigned short* Abf = (unsigned short*)p;          // N*D bf16
  unsigned short* Wt  = Abf + (size_t)N * D;         // 320*512 bf16

  prep_kernel<<<(N * D / 8) / 256, 256, 0, stream>>>(feature, Wm1, W1, Abf, Wt, rowcnt);
  gemm_mfma<<<dim3(320 / 64, N / 64), 256, 0, stream>>>((const bf16x8*)Abf, (const bf16x8*)Wt, bm1, C1, X1);
  mlp_head<<<N / 4, 256, 0, stream>>>(C1, Wm2, bm2, labels1h, mask, Bmat, softy);
  adj_tri<<<N, 256, 0, stream>>>(adj, rowcnt, colidx);
  sort_nbr<<<N / 4, 256, 0, stream>>>(rowcnt, colidx, softy, nbrsum);
  h_partial<<<64, 256, 0, stream>>>(nbrsum, softy, Hpart);
  hq_final<<<1, 256, 0, stream>>>(Hpart, bias, H_o, Q_o, Qws);
  edge_gcn1<<<N / 4, 256, 0, stream>>>(Bmat, Qws, rowcnt, colidx, X1, b1, W2, gval, X2);
  gcn2<<<N / 4, 256, 0, stream>>>(X2, b2, rowcnt, colidx, gval, logits_o, outp_o);
  loss_kernel<<<1, 256, 0, stream>>>(logits_o, Bmat, idx, label, loss_o);
}